// Round 3
// baseline (2451.823 us; speedup 1.0000x reference)
//
#include <hip/hip_runtime.h>
#include <math.h>

#define TT 200
#define S36 36   // LDS leading stride (floats): 16B-aligned, bank-rotating

typedef float v2f __attribute__((ext_vector_type(2)));

__device__ __forceinline__ float rdlane(float v, int l) {
  return __int_as_float(__builtin_amdgcn_readlane(__float_as_int(v), l));
}

#if __has_builtin(__builtin_amdgcn_rsqf)
#define RSQF(x) __builtin_amdgcn_rsqf(x)
#else
#define RSQF(x) (1.0f / sqrtf(x))
#endif

__device__ __forceinline__ float4 ld4(const float* p) { return *(const float4*)p; }
__device__ __forceinline__ void st4(float* p, float4 v) { *(float4*)p = v; }

struct Acc { v2f a[4][2]; };

// D tile (4 rows @R0, 4 cols @C0) of L @ R, where LT[k][i] = L[i][k] (stride 36)
// and RB[k][j] = R[k][j] (stride 36). Both reads are 8-way-broadcast b128.
__device__ __forceinline__ void mm32(const float* __restrict__ LT,
                                     const float* __restrict__ RB,
                                     int R0, int C0, Acc& o) {
  #pragma unroll
  for (int r = 0; r < 4; ++r) { o.a[r][0] = v2f{0.f, 0.f}; o.a[r][1] = v2f{0.f, 0.f}; }
  #pragma unroll 4
  for (int k = 0; k < 32; ++k) {
    float4 lv = ld4(LT + k * S36 + R0);
    float4 rv = ld4(RB + k * S36 + C0);
    v2f r0 = v2f{rv.x, rv.y}, r1 = v2f{rv.z, rv.w};
    float l0 = lv.x, l1 = lv.y, l2 = lv.z, l3 = lv.w;
    o.a[0][0] = __builtin_elementwise_fma(v2f{l0, l0}, r0, o.a[0][0]);
    o.a[0][1] = __builtin_elementwise_fma(v2f{l0, l0}, r1, o.a[0][1]);
    o.a[1][0] = __builtin_elementwise_fma(v2f{l1, l1}, r0, o.a[1][0]);
    o.a[1][1] = __builtin_elementwise_fma(v2f{l1, l1}, r1, o.a[1][1]);
    o.a[2][0] = __builtin_elementwise_fma(v2f{l2, l2}, r0, o.a[2][0]);
    o.a[2][1] = __builtin_elementwise_fma(v2f{l2, l2}, r1, o.a[2][1]);
    o.a[3][0] = __builtin_elementwise_fma(v2f{l3, l3}, r0, o.a[3][0]);
    o.a[3][1] = __builtin_elementwise_fma(v2f{l3, l3}, r1, o.a[3][1]);
  }
}

__device__ __forceinline__ float accE(const Acc& o, int r, int c) {
  return o.a[r][c >> 1][c & 1];
}

// store tile TRANSPOSED into dst (stride 36): dst[C0+c][R0..R0+3] = col c
__device__ __forceinline__ void storeT(float* dst, int R0, int C0, const Acc& o) {
  #pragma unroll
  for (int c = 0; c < 4; ++c) {
    float4 v = {accE(o, 0, c), accE(o, 1, c), accE(o, 2, c), accE(o, 3, c)};
    st4(dst + (C0 + c) * S36 + R0, v);
  }
}

// store tile normally into dst (stride 36)
__device__ __forceinline__ void storeN(float* dst, int R0, int C0, const Acc& o) {
  #pragma unroll
  for (int r = 0; r < 4; ++r) {
    float4 v = {o.a[r][0].x, o.a[r][0].y, o.a[r][1].x, o.a[r][1].y};
    st4(dst + (R0 + r) * S36 + C0, v);
  }
}

__global__ void __launch_bounds__(64) kf_kernel(
    const float* __restrict__ Yg, const float* __restrict__ Ug,
    const float* __restrict__ Mg, const float* __restrict__ Ag,
    const float* __restrict__ Bg, const float* __restrict__ Cg,
    const float* __restrict__ mu0g, const float* __restrict__ S0g,
    const float* __restrict__ Qg, const float* __restrict__ Rg,
    float* __restrict__ out, int Bsz)
{
  __shared__ __align__(16) float AT[32 * S36];   // AT[k][i] = A[i][k]
  __shared__ __align__(16) float CT[32 * S36];   // CT[k][i] = C[i][k]
  __shared__ __align__(16) float BT[16 * S36];   // BT[k][i] = Bm[i][k]
  __shared__ __align__(16) float Sig[32 * S36];  // Sigma_filt (row-major)
  __shared__ __align__(16) float SigP[32 * S36]; // Sigma_pred (row-major)
  __shared__ __align__(16) float T1T[32 * S36];  // (A Sigma)^T
  __shared__ __align__(16) float T2T[32 * S36];  // (C SigP)^T
  __shared__ __align__(16) float STb[32 * S36];  // S^T (row c = column c of S)
  __shared__ __align__(16) float W36[32 * S36];  // W rows (33 cols used)
  __shared__ float r_buf[32];

  const int lane = threadIdx.x;
  const int li = lane & 31;
  const int R0 = (lane >> 3) << 2;   // tile row base 0..28
  const int C0 = (lane & 7) << 2;    // tile col base 0..28
  const int cw = (lane < 35) ? lane : 35;  // W column write slot (33,34,35 = pad)
  const int b = blockIdx.x;
  const long btB = (long)b * TT;

  const long o_Sf = (long)Bsz * TT * 32;
  const long o_mp = o_Sf + (long)Bsz * TT * 1024;
  const long o_Sp = o_mp + (long)Bsz * TT * 32;

  // ---- preload constants + state ----
  for (int e = lane; e < 1024; e += 64) {
    int i = e >> 5, k = e & 31;
    AT[k * S36 + i] = Ag[e];
    CT[k * S36 + i] = Cg[e];
    Sig[i * S36 + k] = S0g[e];
  }
  for (int e = lane; e < 512; e += 64) {
    int i = e >> 4, k = e & 15;
    BT[k * S36 + i] = Bg[e];
  }
  float4 qt[4], rt[4];
  #pragma unroll
  for (int r = 0; r < 4; ++r) {
    qt[r] = *(const float4*)(Qg + (R0 + r) * 32 + C0);
    rt[r] = *(const float4*)(Rg + (R0 + r) * 32 + C0);
  }
  float mu = mu0g[li];
  __syncthreads();

  for (int t = 0; t < TT; ++t) {
    const long bt = btB + t;
    const float u_r = Ug[bt * 16 + (lane & 15)];
    const float y_r = Yg[bt * 32 + li];
    const float m = Mg[bt];

    // ---- P1: T1 = A @ Sigma -> T1T ----
    {
      Acc o; mm32(AT, Sig, R0, C0, o);
      storeT(T1T, R0, C0, o);
    }
    __syncthreads();

    // ---- P2: SigP = T1 @ A^T + Q ; mu_pred = A mu + Bm u ----
    Acc sp;
    float mp;
    {
      mm32(T1T, AT, R0, C0, sp);
      #pragma unroll
      for (int r = 0; r < 4; ++r) {
        sp.a[r][0].x += qt[r].x; sp.a[r][0].y += qt[r].y;
        sp.a[r][1].x += qt[r].z; sp.a[r][1].y += qt[r].w;
      }
      storeN(SigP, R0, C0, sp);
      // global Sigma_pred (from regs)
      #pragma unroll
      for (int r = 0; r < 4; ++r) {
        float4 v = {sp.a[r][0].x, sp.a[r][0].y, sp.a[r][1].x, sp.a[r][1].y};
        st4(out + o_Sp + bt * 1024 + (R0 + r) * 32 + C0, v);
      }
      mp = 0.f;
      #pragma unroll 4
      for (int k = 0; k < 32; ++k) mp = fmaf(AT[k * S36 + li], rdlane(mu, k), mp);
      #pragma unroll 4
      for (int k = 0; k < 16; ++k) mp = fmaf(BT[k * S36 + li], rdlane(u_r, k), mp);
      if (lane < 32) out[o_mp + bt * 32 + lane] = mp;
    }
    __syncthreads();

    // ---- P3: T2 = C @ SigP -> T2T ; r = y - C mu_pred ----
    {
      Acc o; mm32(CT, SigP, R0, C0, o);
      storeT(T2T, R0, C0, o);
      float rv = y_r;
      #pragma unroll 4
      for (int k = 0; k < 32; ++k) rv = fmaf(-CT[k * S36 + li], rdlane(mp, k), rv);
      if (lane < 32) r_buf[lane] = rv;
    }
    __syncthreads();

    // ---- P4: S = T2 @ C^T + R -> STb (=S^T) ----
    {
      Acc o; mm32(T2T, CT, R0, C0, o);
      #pragma unroll
      for (int r = 0; r < 4; ++r) {
        o.a[r][0].x += rt[r].x; o.a[r][0].y += rt[r].y;
        o.a[r][1].x += rt[r].z; o.a[r][1].y += rt[r].w;
      }
      storeT(STb, R0, C0, o);
    }
    __syncthreads();

    // ---- P5: fused Cholesky + forward substitution (whole wave, in-register)
    //      lane c owns chol column c (c<32) and RHS column c of [T2 | r] ----
    float w[32], rr[32];
    {
      const int crow = (lane < 32) ? lane : 31;
      const float* rp = (lane < 32) ? (T2T + lane * S36) : r_buf;
      #pragma unroll
      for (int q = 0; q < 8; ++q) {
        float4 wv = ld4(STb + crow * S36 + 4 * q);
        w[4 * q] = wv.x; w[4 * q + 1] = wv.y; w[4 * q + 2] = wv.z; w[4 * q + 3] = wv.w;
        float4 rv = ld4(rp + 4 * q);
        rr[4 * q] = rv.x; rr[4 * q + 1] = rv.y; rr[4 * q + 2] = rv.z; rr[4 * q + 3] = rv.w;
      }
      #pragma unroll
      for (int j = 0; j < 32; ++j) {
        float d = rdlane(w[j], j);      // pivot (wave-uniform)
        float s = RSQF(d);
        float wjs2 = w[j] * s * s;      // per-lane chol coefficient
        float zj = rr[j] * s;
        float szj = s * zj;
        rr[j] = zj;
        W36[j * S36 + cw] = zj;         // W row j (cols 33-35 are pad)
        #pragma unroll
        for (int i = j + 1; i < 32; ++i) {
          float bw = rdlane(w[i], j);   // column j below diag, from lane j
          w[i]  = fmaf(-bw, wjs2, w[i]);
          rr[i] = fmaf(-bw, szj, rr[i]);
        }
      }
      // mu_new = mu_pred + m * sum_p W[p][i] * z_r[p]  (all in registers)
      float sacc = 0.f;
      #pragma unroll
      for (int p = 0; p < 32; ++p) sacc = fmaf(rr[p], rdlane(rr[p], 32), sacc);
      mu = fmaf(m, sacc, mp);
      if (lane < 32) out[bt * 32 + lane] = mu;
    }
    __syncthreads();

    // ---- P6: G = W^T W ; Sigma' = SigP + (m^2 - 2m) G ----
    {
      Acc g; mm32(W36, W36, R0, C0, g);
      const float coef = fmaf(m, m, -2.f * m);
      #pragma unroll
      for (int r = 0; r < 4; ++r) {
        #pragma unroll
        for (int h = 0; h < 2; ++h) {
          g.a[r][h].x = fmaf(coef, g.a[r][h].x, sp.a[r][h].x);
          g.a[r][h].y = fmaf(coef, g.a[r][h].y, sp.a[r][h].y);
        }
      }
      storeN(Sig, R0, C0, g);
      #pragma unroll
      for (int r = 0; r < 4; ++r) {
        float4 v = {g.a[r][0].x, g.a[r][0].y, g.a[r][1].x, g.a[r][1].y};
        st4(out + o_Sf + bt * 1024 + (R0 + r) * 32 + C0, v);
      }
    }
    __syncthreads();
  }
}

extern "C" void kernel_launch(void* const* d_in, const int* in_sizes, int n_in,
                              void* d_out, int out_size, void* d_ws, size_t ws_size,
                              hipStream_t stream) {
  const float* Y   = (const float*)d_in[0];
  const float* U   = (const float*)d_in[1];
  const float* Mk  = (const float*)d_in[2];
  const float* A   = (const float*)d_in[3];
  const float* Bm  = (const float*)d_in[4];
  const float* C   = (const float*)d_in[5];
  const float* mu0 = (const float*)d_in[6];
  const float* S0  = (const float*)d_in[7];
  const float* Q   = (const float*)d_in[8];
  const float* R   = (const float*)d_in[9];
  int Bsz = in_sizes[2] / TT;
  kf_kernel<<<Bsz, 64, 0, stream>>>(Y, U, Mk, A, Bm, C, mu0, S0, Q, R,
                                    (float*)d_out, Bsz);
}